// Round 7
// baseline (108.392 us; speedup 1.0000x reference)
//
#include <hip/hip_runtime.h>

#define LQ   4096
#define HDIM 64
// keep iff (bits>>9) < 0.9f*2^23  <=>  bits < (7549747u<<9)
#define KEEP_LIMIT (7549747u << 9)
// 0.125 * log2(e)
#define SCALE_LOG2E 0.18033688011112042f

typedef __attribute__((ext_vector_type(8))) short short8v;
typedef __attribute__((ext_vector_type(4))) short short4v;
typedef __attribute__((ext_vector_type(4))) float f32x4;

__device__ __forceinline__ unsigned rotl32(unsigned x, int r) {
  return (x << r) | (x >> (32 - r));
}

// Threefry-2x32, key=(0,42), partitionable mode: bits(j) = o0^o1 of (0, j)
__device__ __forceinline__ float keep_sel(unsigned j, float e) {
  const unsigned ks1 = 42u;
  const unsigned ks2 = 0x1BD11BDAu ^ 42u;
  unsigned x0 = 0u, x1 = j + ks1;
#define TFR(r) { x0 += x1; x1 = rotl32(x1, r); x1 ^= x0; }
  TFR(13) TFR(15) TFR(26) TFR(6)   x0 += ks1; x1 += ks2 + 1u;
  TFR(17) TFR(29) TFR(16) TFR(24)  x0 += ks2; x1 += 0u  + 2u;
  TFR(13) TFR(15) TFR(26) TFR(6)   x0 += 0u;  x1 += ks1 + 3u;
  TFR(17) TFR(29) TFR(16) TFR(24)  x0 += ks1; x1 += ks2 + 4u;
  TFR(13) TFR(15) TFR(26) TFR(6)   x0 += ks2; x1 += 0u  + 5u;
#undef TFR
  return ((x0 ^ x1) < KEEP_LIMIT) ? e : 0.f;
}

// f32 -> bf16 RNE (cold paths)
__device__ __forceinline__ unsigned short f2bf(float x) {
  unsigned u = __float_as_uint(x);
  u += 0x7fffu + ((u >> 16) & 1u);
  return (unsigned short)(u >> 16);
}

// async global->LDS, 16B/lane; LDS dest = wave-uniform base (+ lane*16 by HW)
__device__ __forceinline__ void gload16(const void* g, void* l) {
  __builtin_amdgcn_global_load_lds(
      (const __attribute__((address_space(1))) unsigned int*)g,
      (__attribute__((address_space(3))) unsigned int*)l, 16, 0, 0);
}

#if __has_builtin(__builtin_amdgcn_mfma_f32_16x16x16bf16_1k)
#define MFMA16(a, b, c) __builtin_amdgcn_mfma_f32_16x16x16bf16_1k(a, b, c, 0, 0, 0)
#else
__device__ __forceinline__ f32x4 mfma16_asm(short4v a, short4v b, f32x4 c) {
  f32x4 d;
  asm volatile("v_mfma_f32_16x16x16_bf16 %0, %1, %2, %3"
               : "=v"(d) : "v"(a), "v"(b), "v"(c));
  return d;
}
#define MFMA16(a, b, c) mfma16_asm(a, b, c)
#endif

// ---- pre-pass: K cast to bf16 row-major; V cast+transpose to VT[b][h][L] ---
__global__ __launch_bounds__(256) void prep(const float* __restrict__ k,
                                            const float* __restrict__ v,
                                            unsigned short* __restrict__ kb,
                                            unsigned short* __restrict__ vtb) {
  __shared__ float t[64][65];
  const int b = blockIdx.y, tl = blockIdx.x;
  const int tid = threadIdx.x, lane = tid & 63, grp = tid >> 6;
  {
    const float* kp = k + ((size_t)b * LQ + tl * 64) * HDIM;
    unsigned short* kbp = kb + ((size_t)b * LQ + tl * 64) * HDIM;
#pragma unroll
    for (int i = 0; i < 4; i++) {
      int e = (i * 256 + tid) * 4;
      float4 x = *(const float4*)(kp + e);
      ushort4 y;
      y.x = f2bf(x.x); y.y = f2bf(x.y); y.z = f2bf(x.z); y.w = f2bf(x.w);
      *(ushort4*)(kbp + e) = y;
    }
  }
#pragma unroll
  for (int c = 0; c < 16; c++) {
    int r = c * 4 + grp;
    t[r][lane] = v[((size_t)b * LQ + tl * 64 + r) * HDIM + lane];
  }
  __syncthreads();
#pragma unroll
  for (int c = 0; c < 16; c++) {
    int h = c * 4 + grp;
    vtb[((size_t)b * HDIM + h) * LQ + tl * 64 + lane] = f2bf(t[lane][h]);
  }
}

// ---------------- MFMA flash attention + exact-JAX dropout ------------------
// grid 2048: tile16 = 255-(bx>>3) (longest first), b = (bx>>1)&3, s = bx&1.
// Split-KV: block s handles half the causal KV-tile range; partial O/lsum
// combined via f32 atomicAdd (no online max -> pure sums). 4 waves =
// kv-quarters. K fragments read direct from global (L2-resident),
// register-double-buffered. Only V staged in LDS (16 KB -> 8 blocks/CU).
__global__ __launch_bounds__(256, 8) void attn(
    const float* __restrict__ q, const unsigned short* __restrict__ kb,
    const unsigned short* __restrict__ vtb, float* __restrict__ o,
    float* __restrict__ plsum) {
  __shared__ __align__(16) unsigned short vl[2][64 * 64];  // 16 KB

  const int bx = blockIdx.x;
  const int tile16 = 255 - (bx >> 3);
  const int b = (bx >> 1) & 3;
  const int s = bx & 1;
  const int tid = threadIdx.x, lane = tid & 63, wq = tid >> 6;
  const int g = lane >> 4, r = lane & 15;
  const int qrow = tile16 * 16 + r;
  const int nt = (tile16 >> 2) + 1;
  const int half = (nt + 1) >> 1;
  const int ts = s ? half : 0, te = s ? nt : half;
  const int ntm1 = nt - 1;
  const unsigned sw = (unsigned)((r & 7) << 4);

  // ---- Q B-frags (persistent) ----
  short8v qf0, qf1;
  {
    const float* qp = q + ((size_t)b * LQ + qrow) * HDIM + g * 8;
    float4 a0 = *(const float4*)qp;
    float4 a1 = *(const float4*)(qp + 4);
    float4 b0 = *(const float4*)(qp + 32);
    float4 b1 = *(const float4*)(qp + 36);
    qf0[0] = (short)f2bf(a0.x); qf0[1] = (short)f2bf(a0.y);
    qf0[2] = (short)f2bf(a0.z); qf0[3] = (short)f2bf(a0.w);
    qf0[4] = (short)f2bf(a1.x); qf0[5] = (short)f2bf(a1.y);
    qf0[6] = (short)f2bf(a1.z); qf0[7] = (short)f2bf(a1.w);
    qf1[0] = (short)f2bf(b0.x); qf1[1] = (short)f2bf(b0.y);
    qf1[2] = (short)f2bf(b0.z); qf1[3] = (short)f2bf(b0.w);
    qf1[4] = (short)f2bf(b1.x); qf1[5] = (short)f2bf(b1.y);
    qf1[6] = (short)f2bf(b1.z); qf1[7] = (short)f2bf(b1.w);
  }

  // ---- hoisted per-lane staging source offsets (V) and K base pointer ----
  const char* vt_b = (const char*)vtb + (size_t)b * HDIM * LQ * 2;
  unsigned vsrc0, vsrc1;
  {
    unsigned d0 = (unsigned)(tid * 16);
    unsigned d1 = d0 + 4096u;
    vsrc0 = (d0 >> 7) * (LQ * 2) + ((d0 & 127u) ^ (((d0 >> 7) & 7u) << 4));
    vsrc1 = (d1 >> 7) * (LQ * 2) + ((d1 & 127u) ^ (((d1 >> 7) & 7u) << 4));
  }
  const char* kbl =
      (const char*)kb + ((size_t)b * LQ + wq * 16 + r) * 128 + g * 16;

#define STAGE(T, BI)                                                           \
  {                                                                            \
    gload16(vt_b + vsrc0 + (size_t)(T) * 128,                                  \
            (char*)&vl[BI][0] + wq * 1024);                                    \
    gload16(vt_b + vsrc1 + (size_t)(T) * 128,                                  \
            (char*)&vl[BI][0] + wq * 1024 + 4096);                             \
  }

  f32x4 acc[4];
  acc[0] = (f32x4){0, 0, 0, 0}; acc[1] = (f32x4){0, 0, 0, 0};
  acc[2] = (f32x4){0, 0, 0, 0}; acc[3] = (f32x4){0, 0, 0, 0};
  float lsum = 0.f;

  short8v k0c, k1c;
  if (ts < te) {
    STAGE(ts, 0)
    k0c = *(const short8v*)(kbl + (size_t)ts * 8192);
    k1c = *(const short8v*)(kbl + (size_t)ts * 8192 + 64);
  }
  __syncthreads();

  for (int t = ts; t < te; ++t) {
    const int bi = (t - ts) & 1;
    short8v k0n, k1n;
    const bool more = (t + 1 < te);
    if (more) {
      STAGE(t + 1, bi ^ 1)
      k0n = *(const short8v*)(kbl + (size_t)(t + 1) * 8192);
      k1n = *(const short8v*)(kbl + (size_t)(t + 1) * 8192 + 64);
    }

    f32x4 S = __builtin_amdgcn_mfma_f32_16x16x32_bf16(k0c, qf0,
                                                      (f32x4){0, 0, 0, 0}, 0, 0, 0);
    S = __builtin_amdgcn_mfma_f32_16x16x32_bf16(k1c, qf1, S, 0, 0, 0);

    // ---- exp + threefry dropout (lane-local) ----
    const int kvb = t * 64 + wq * 16 + g * 4;
    const unsigned jb =
        ((unsigned)b << 24) | ((unsigned)qrow << 12) | (unsigned)kvb;
    float w[4];
    if (t == ntm1) {   // diagonal tile: causal mask needed (wave-uniform branch)
#pragma unroll
      for (int reg = 0; reg < 4; ++reg) {
        float e = (kvb + reg <= qrow) ? exp2f(S[reg] * SCALE_LOG2E) : 0.f;
        lsum += e;
        w[reg] = keep_sel(jb + (unsigned)reg, e);
      }
    } else {
#pragma unroll
      for (int reg = 0; reg < 4; ++reg) {
        float e = exp2f(S[reg] * SCALE_LOG2E);
        lsum += e;
        w[reg] = keep_sel(jb + (unsigned)reg, e);
      }
    }

    // ---- pack P to bf16 A-frag via v_cvt_pk_bf16_f32 ----
    union { unsigned u[2]; short4v s4; } pu;
    asm("v_cvt_pk_bf16_f32 %0, %1, %2" : "=v"(pu.u[0]) : "v"(w[0]), "v"(w[1]));
    asm("v_cvt_pk_bf16_f32 %0, %1, %2" : "=v"(pu.u[1]) : "v"(w[2]), "v"(w[3]));
    const short4v pa = pu.s4;

    // ---- PV: 4 h-groups, K=16 mfma; B-frag from swizzled VT LDS ----
    const char* vlp = (const char*)&vl[bi][0] + r * 128 +
                      (((unsigned)(wq * 32 + g * 8)) ^ sw);
#pragma unroll
    for (int hg = 0; hg < 4; ++hg) {
      short4v vf = *(const short4v*)(vlp + hg * 2048);
      acc[hg] = MFMA16(pa, vf, acc[hg]);
    }
    __syncthreads();
    if (more) { k0c = k0n; k1c = k1n; }
  }
#undef STAGE

  // ---- epilogue: atomic combine of partials ----
  lsum += __shfl_xor(lsum, 16);
  lsum += __shfl_xor(lsum, 32);
  if (lane < 16)
    atomicAdd(&plsum[b * LQ + tile16 * 16 + lane], lsum);

  float* ob = o + ((size_t)b * LQ + tile16 * 16) * HDIM;
#pragma unroll
  for (int hg = 0; hg < 4; ++hg)
#pragma unroll
    for (int reg = 0; reg < 4; ++reg)
      atomicAdd(&ob[(g * 4 + reg) * HDIM + hg * 16 + r], acc[hg][reg]);
}

// ---- normalize: out /= (lsum * keep_p) ----
__global__ __launch_bounds__(256) void norm(float* __restrict__ o,
                                            const float* __restrict__ plsum) {
  const int idx = blockIdx.x * 256 + threadIdx.x;   // 262144 float4s
  f32x4 x = ((const f32x4*)o)[idx];
  const float inv = 1.0f / (plsum[idx >> 4] * 0.9f);
  ((f32x4*)o)[idx] = x * inv;
}

extern "C" void kernel_launch(void* const* d_in, const int* in_sizes, int n_in,
                              void* d_out, int out_size, void* d_ws, size_t ws_size,
                              hipStream_t stream) {
  const float* q = (const float*)d_in[0];
  const float* k = (const float*)d_in[1];
  const float* v = (const float*)d_in[2];
  float* out = (float*)d_out;
  unsigned short* kb  = (unsigned short*)d_ws;            // [0, 2 MB) bf16 K
  unsigned short* vtb = kb + (size_t)4 * LQ * HDIM;       // [2 MB, 4 MB) bf16 V^T
  float* plsum = (float*)((char*)d_ws + (size_t)4 * 1024 * 1024);  // [4 MB, +64 KB)

  hipMemsetAsync(out, 0, (size_t)4 * LQ * HDIM * sizeof(float), stream);
  hipMemsetAsync(plsum, 0, (size_t)4 * LQ * sizeof(float), stream);
  prep<<<dim3(64, 4), 256, 0, stream>>>(k, v, kb, vtb);
  attn<<<2048, 256, 0, stream>>>(q, kb, vtb, out, plsum);
  norm<<<1024, 256, 0, stream>>>(out, plsum);
}

// Round 8
// 96.583 us; speedup vs baseline: 1.1223x; 1.1223x over previous
//
#include <hip/hip_runtime.h>

#define LQ   4096
#define HDIM 64
// keep iff (bits>>9) < 0.9f*2^23  <=>  bits < (7549747u<<9)
#define KEEP_LIMIT (7549747u << 9)
// 0.125 * log2(e)
#define SCALE_LOG2E 0.18033688011112042f

typedef __attribute__((ext_vector_type(8))) short short8v;
typedef __attribute__((ext_vector_type(4))) short short4v;
typedef __attribute__((ext_vector_type(4))) float f32x4;

__device__ __forceinline__ unsigned rotl32(unsigned x, int r) {
  return (x << r) | (x >> (32 - r));
}

// Threefry-2x32, key=(0,42), partitionable mode: bits(j) = o0^o1 of (0, j)
__device__ __forceinline__ float keep_sel(unsigned j, float e) {
  const unsigned ks1 = 42u;
  const unsigned ks2 = 0x1BD11BDAu ^ 42u;
  unsigned x0 = 0u, x1 = j + ks1;
#define TFR(r) { x0 += x1; x1 = rotl32(x1, r); x1 ^= x0; }
  TFR(13) TFR(15) TFR(26) TFR(6)   x0 += ks1; x1 += ks2 + 1u;
  TFR(17) TFR(29) TFR(16) TFR(24)  x0 += ks2; x1 += 0u  + 2u;
  TFR(13) TFR(15) TFR(26) TFR(6)   x0 += 0u;  x1 += ks1 + 3u;
  TFR(17) TFR(29) TFR(16) TFR(24)  x0 += ks1; x1 += ks2 + 4u;
  TFR(13) TFR(15) TFR(26) TFR(6)   x0 += ks2; x1 += 0u  + 5u;
#undef TFR
  return ((x0 ^ x1) < KEEP_LIMIT) ? e : 0.f;
}

// f32 -> bf16 RNE (cold paths)
__device__ __forceinline__ unsigned short f2bf(float x) {
  unsigned u = __float_as_uint(x);
  u += 0x7fffu + ((u >> 16) & 1u);
  return (unsigned short)(u >> 16);
}

// async global->LDS, 16B/lane; LDS dest = wave-uniform base (+ lane*16 by HW)
__device__ __forceinline__ void gload16(const void* g, void* l) {
  __builtin_amdgcn_global_load_lds(
      (const __attribute__((address_space(1))) unsigned int*)g,
      (__attribute__((address_space(3))) unsigned int*)l, 16, 0, 0);
}

#if __has_builtin(__builtin_amdgcn_mfma_f32_16x16x16bf16_1k)
#define MFMA16(a, b, c) __builtin_amdgcn_mfma_f32_16x16x16bf16_1k(a, b, c, 0, 0, 0)
#else
__device__ __forceinline__ f32x4 mfma16_asm(short4v a, short4v b, f32x4 c) {
  f32x4 d;
  asm volatile("v_mfma_f32_16x16x16_bf16 %0, %1, %2, %3"
               : "=v"(d) : "v"(a), "v"(b), "v"(c));
  return d;
}
#define MFMA16(a, b, c) mfma16_asm(a, b, c)
#endif

// ---- pre-pass: K cast to bf16 row-major; V cast+transpose to VT[b][h][L] ---
__global__ __launch_bounds__(256) void prep(const float* __restrict__ k,
                                            const float* __restrict__ v,
                                            unsigned short* __restrict__ kb,
                                            unsigned short* __restrict__ vtb) {
  __shared__ float t[64][65];
  const int b = blockIdx.y, tl = blockIdx.x;
  const int tid = threadIdx.x, lane = tid & 63, grp = tid >> 6;
  {
    const float* kp = k + ((size_t)b * LQ + tl * 64) * HDIM;
    unsigned short* kbp = kb + ((size_t)b * LQ + tl * 64) * HDIM;
#pragma unroll
    for (int i = 0; i < 4; i++) {
      int e = (i * 256 + tid) * 4;
      float4 x = *(const float4*)(kp + e);
      ushort4 y;
      y.x = f2bf(x.x); y.y = f2bf(x.y); y.z = f2bf(x.z); y.w = f2bf(x.w);
      *(ushort4*)(kbp + e) = y;
    }
  }
#pragma unroll
  for (int c = 0; c < 16; c++) {
    int r = c * 4 + grp;
    t[r][lane] = v[((size_t)b * LQ + tl * 64 + r) * HDIM + lane];
  }
  __syncthreads();
#pragma unroll
  for (int c = 0; c < 16; c++) {
    int h = c * 4 + grp;
    vtb[((size_t)b * HDIM + h) * LQ + tl * 64 + lane] = f2bf(t[lane][h]);
  }
}

// ---------------- MFMA flash attention + exact-JAX dropout ------------------
// grid 2048: tile16 = 255-(bx>>3) (longest first), b = (bx>>1)&3, s = bx&1.
// Split-KV halves per q-tile, partials combined via f32 atomicAdd.
// 2 KV-tiles per loop iteration: 4 LDS V-buffers, one barrier per pair;
// K register-double-buffered one pair ahead. 128-VGPR budget for 8-chain
// threefry ILP.
__global__ __launch_bounds__(256, 4) void attn(
    const float* __restrict__ q, const unsigned short* __restrict__ kb,
    const unsigned short* __restrict__ vtb, float* __restrict__ o,
    float* __restrict__ plsum) {
  __shared__ __align__(16) unsigned short vl[4][64 * 64];  // 32 KB

  const int bx = blockIdx.x;
  const int tile16 = 255 - (bx >> 3);
  const int b = (bx >> 1) & 3;
  const int s = bx & 1;
  const int tid = threadIdx.x, lane = tid & 63, wq = tid >> 6;
  const int g = lane >> 4, r = lane & 15;
  const int qrow = tile16 * 16 + r;
  const int nt = (tile16 >> 2) + 1;
  const int half = (nt + 1) >> 1;
  const int ts = s ? half : 0, te = s ? nt : half;
  const int ntm1 = nt - 1;
  const unsigned sw = (unsigned)((r & 7) << 4);
  const unsigned jq = ((unsigned)b << 24) | ((unsigned)qrow << 12);
  const f32x4 zero4 = (f32x4){0.f, 0.f, 0.f, 0.f};

  // ---- Q B-frags (persistent) ----
  short8v qf0, qf1;
  {
    const float* qp = q + ((size_t)b * LQ + qrow) * HDIM + g * 8;
    float4 a0 = *(const float4*)qp;
    float4 a1 = *(const float4*)(qp + 4);
    float4 b0 = *(const float4*)(qp + 32);
    float4 b1 = *(const float4*)(qp + 36);
    qf0[0] = (short)f2bf(a0.x); qf0[1] = (short)f2bf(a0.y);
    qf0[2] = (short)f2bf(a0.z); qf0[3] = (short)f2bf(a0.w);
    qf0[4] = (short)f2bf(a1.x); qf0[5] = (short)f2bf(a1.y);
    qf0[6] = (short)f2bf(a1.z); qf0[7] = (short)f2bf(a1.w);
    qf1[0] = (short)f2bf(b0.x); qf1[1] = (short)f2bf(b0.y);
    qf1[2] = (short)f2bf(b0.z); qf1[3] = (short)f2bf(b0.w);
    qf1[4] = (short)f2bf(b1.x); qf1[5] = (short)f2bf(b1.y);
    qf1[6] = (short)f2bf(b1.z); qf1[7] = (short)f2bf(b1.w);
  }

  // ---- staging pointers (strength-reduced) ----
  const char* vt_b = (const char*)vtb + (size_t)b * HDIM * LQ * 2;
  const char* vpA;
  const char* vpB;
  {
    unsigned d0 = (unsigned)(tid * 16);
    unsigned d1 = d0 + 4096u;
    unsigned vsrc0 = (d0 >> 7) * (LQ * 2) + ((d0 & 127u) ^ (((d0 >> 7) & 7u) << 4));
    unsigned vsrc1 = (d1 >> 7) * (LQ * 2) + ((d1 & 127u) ^ (((d1 >> 7) & 7u) << 4));
    vpA = vt_b + vsrc0 + (size_t)ts * 128;   // tracks tile t
    vpB = vt_b + vsrc1 + (size_t)ts * 128;
  }
  const char* kp =
      (const char*)kb + ((size_t)b * LQ + wq * 16 + r) * 128 + g * 16 +
      (size_t)ts * 8192;                      // tracks next K pair to load

  char* const lw = (char*)&vl[0][0] + wq * 1024;   // wave's LDS write base

  f32x4 acc[4];
  acc[0] = zero4; acc[1] = zero4; acc[2] = zero4; acc[3] = zero4;
  float lsum = 0.f;

  // ---- prologue: stage pair (ts, ts+1), load K pair ----
  const int n = te - ts;
  short8v kA0 = {}, kA1 = {}, kB0 = {}, kB1 = {};
  if (n > 0) {
    gload16(vpA, lw);
    gload16(vpB, lw + 4096);
    kA0 = *(const short8v*)(kp);
    kA1 = *(const short8v*)(kp + 64);
  }
  if (n > 1) {
    gload16(vpA + 128, lw + 8192);
    gload16(vpB + 128, lw + 8192 + 4096);
    kB0 = *(const short8v*)(kp + 8192);
    kB1 = *(const short8v*)(kp + 8192 + 64);
  }
  kp += 16384;   // now points at pair (ts+2, ts+3)
  __syncthreads();

#define COMPUTE_TILE(K0, K1, BUFI, T, DIAG)                                    \
  {                                                                            \
    const char* vlp = (const char*)&vl[BUFI][0] + r * 128 +                    \
                      (((unsigned)(wq * 32 + g * 8)) ^ sw);                    \
    short4v vf[4];                                                             \
    _Pragma("unroll") for (int hg = 0; hg < 4; ++hg)                           \
        vf[hg] = *(const short4v*)(vlp + hg * 2048);                           \
    f32x4 S = __builtin_amdgcn_mfma_f32_16x16x32_bf16(K0, qf0, zero4, 0, 0, 0);\
    S = __builtin_amdgcn_mfma_f32_16x16x32_bf16(K1, qf1, S, 0, 0, 0);          \
    const int kvb = (T) * 64 + wq * 16 + g * 4;                                \
    float w[4];                                                                \
    if (DIAG) {                                                                \
      _Pragma("unroll") for (int reg = 0; reg < 4; ++reg) {                    \
        float e = (kvb + reg <= qrow) ? exp2f(S[reg] * SCALE_LOG2E) : 0.f;     \
        lsum += e;                                                             \
        w[reg] = keep_sel(jq | (unsigned)(kvb + reg), e);                      \
      }                                                                        \
    } else {                                                                   \
      _Pragma("unroll") for (int reg = 0; reg < 4; ++reg) {                    \
        float e = exp2f(S[reg] * SCALE_LOG2E);                                 \
        lsum += e;                                                             \
        w[reg] = keep_sel(jq | (unsigned)(kvb + reg), e);                      \
      }                                                                        \
    }                                                                          \
    union { unsigned u[2]; short4v s4; } pu;                                   \
    asm("v_cvt_pk_bf16_f32 %0, %1, %2" : "=v"(pu.u[0]) : "v"(w[0]), "v"(w[1]));\
    asm("v_cvt_pk_bf16_f32 %0, %1, %2" : "=v"(pu.u[1]) : "v"(w[2]), "v"(w[3]));\
    const short4v pa = pu.s4;                                                  \
    _Pragma("unroll") for (int hg = 0; hg < 4; ++hg)                           \
        acc[hg] = MFMA16(pa, vf[hg], acc[hg]);                                 \
  }

  int t = ts;
  int base = 0;
  for (; t + 2 <= te; t += 2) {
    // prefetch next pair (V -> LDS, K -> regs)
    short8v nA0 = kA0, nA1 = kA1, nB0 = kB0, nB1 = kB1;
    char* const lwn = lw + (base ^ 2) * 8192;
    if (t + 2 < te) {
      gload16(vpA + 256, lwn);
      gload16(vpB + 256, lwn + 4096);
      nA0 = *(const short8v*)(kp);
      nA1 = *(const short8v*)(kp + 64);
    }
    if (t + 3 < te) {
      gload16(vpA + 384, lwn + 8192);
      gload16(vpB + 384, lwn + 8192 + 4096);
      nB0 = *(const short8v*)(kp + 8192);
      nB1 = *(const short8v*)(kp + 8192 + 64);
    }

    COMPUTE_TILE(kA0, kA1, base, t, false)
    COMPUTE_TILE(kB0, kB1, base + 1, t + 1, (t + 1) == ntm1)

    __syncthreads();   // next pair staged; this pair's LDS reads done
    kA0 = nA0; kA1 = nA1; kB0 = nB0; kB1 = nB1;
    vpA += 256; vpB += 256; kp += 16384;
    base ^= 2;
  }
  if (t < te) {   // odd tail (tile staged into vl[base])
    COMPUTE_TILE(kA0, kA1, base, t, t == ntm1)
  }
#undef COMPUTE_TILE

  // ---- epilogue: atomic combine of partials ----
  lsum += __shfl_xor(lsum, 16);
  lsum += __shfl_xor(lsum, 32);
  if (lane < 16)
    atomicAdd(&plsum[b * LQ + tile16 * 16 + lane], lsum);

  float* ob = o + ((size_t)b * LQ + tile16 * 16) * HDIM;
#pragma unroll
  for (int hg = 0; hg < 4; ++hg)
#pragma unroll
    for (int reg = 0; reg < 4; ++reg)
      atomicAdd(&ob[(g * 4 + reg) * HDIM + hg * 16 + r], acc[hg][reg]);
}

// ---- normalize: out /= (lsum * keep_p) ----
__global__ __launch_bounds__(256) void norm(float* __restrict__ o,
                                            const float* __restrict__ plsum) {
  const int idx = blockIdx.x * 256 + threadIdx.x;   // 262144 float4s
  f32x4 x = ((const f32x4*)o)[idx];
  const float inv = 1.0f / (plsum[idx >> 4] * 0.9f);
  ((f32x4*)o)[idx] = x * inv;
}

extern "C" void kernel_launch(void* const* d_in, const int* in_sizes, int n_in,
                              void* d_out, int out_size, void* d_ws, size_t ws_size,
                              hipStream_t stream) {
  const float* q = (const float*)d_in[0];
  const float* k = (const float*)d_in[1];
  const float* v = (const float*)d_in[2];
  float* out = (float*)d_out;
  unsigned short* kb  = (unsigned short*)d_ws;            // [0, 2 MB) bf16 K
  unsigned short* vtb = kb + (size_t)4 * LQ * HDIM;       // [2 MB, 4 MB) bf16 V^T
  float* plsum = (float*)((char*)d_ws + (size_t)4 * 1024 * 1024);  // [4 MB, +64 KB)

  hipMemsetAsync(out, 0, (size_t)4 * LQ * HDIM * sizeof(float), stream);
  hipMemsetAsync(plsum, 0, (size_t)4 * LQ * sizeof(float), stream);
  prep<<<dim3(64, 4), 256, 0, stream>>>(k, v, kb, vtb);
  attn<<<2048, 256, 0, stream>>>(q, kb, vtb, out, plsum);
  norm<<<1024, 256, 0, stream>>>(out, plsum);
}